// Round 3
// baseline (308.782 us; speedup 1.0000x reference)
//
#include <hip/hip_runtime.h>
#include <hip/hip_bf16.h>
#include <math.h>

#define NLAT 255
#define NPIX 49152

// ---------------- ring geometry (NSIDE=64, compile-time closed forms) -------
__device__ __forceinline__ void ring_params(int t, int& n, int& roff) {
    if (t < 63)        { n = 4 * (t + 1); roff = 2 * t * (t + 1); }
    else if (t <= 191) { n = 256;         roff = 8064 + 256 * (t - 63); }
    else               { int w = 255 - t; n = 4 * w; roff = 49152 - 2 * w * (w + 1); }
}

// ---------------- kernel 1: transpose x[bc][l][m] -> xT[m][l][bc] -----------
__global__ __launch_bounds__(256) void k_transpose(
        const float* __restrict__ xr, const float* __restrict__ xi,
        float* __restrict__ xTr, float* __restrict__ xTi) {
    __shared__ float tile[32][33];
    const int l   = blockIdx.x;          // 0..95
    const int bc0 = blockIdx.y * 32;     // 0..224
    const int z   = blockIdx.z;          // 0..5
    const int comp = z / 3;
    const int m0   = (z % 3) * 32;
    const float* in  = comp ? xi : xr;
    float*       out = comp ? xTi : xTr;
    const int tx = threadIdx.x;          // 0..31
    const int ty = threadIdx.y;          // 0..7
#pragma unroll
    for (int j = 0; j < 4; ++j) {
        int bcl = ty + j * 8;
        tile[bcl][tx] = in[((bc0 + bcl) * 96 + l) * 96 + m0 + tx];
    }
    __syncthreads();
#pragma unroll
    for (int j = 0; j < 4; ++j) {
        int ml = ty + j * 8;
        out[((m0 + ml) * 96 + l) * 256 + bc0 + tx] = tile[tx][ml];
    }
}

// ---------------- kernel 2: Legendre contraction + phase --------------------
// X[t][m][bc] = sc_m * e^{i off[t,m]} * sum_l pct[m,l,t] * x[bc,l,m]
// sc_m = 1 for m=0, 2 otherwise (irfft doubling folded in here).
// Thread tile: 4t x 4bc outer product -> 1 ds_read_b128 per l feeds 32 FMA.
__global__ __launch_bounds__(256) void k_legendre(
        const float* __restrict__ xTr, const float* __restrict__ xTi,
        const float* __restrict__ pct, const float* __restrict__ off,
        float2* __restrict__ X) {
    __shared__ float pcts[96 * 32];     // [l][tt]
    __shared__ float ofs[32];
    const int m   = blockIdx.x;         // 0..95
    const int t0  = blockIdx.y * 32;    // 0..224
    const int bc0 = blockIdx.z * 128;   // 0 or 128
    const int tid = threadIdx.x;
    const int bcg = tid & 31;           // bc group (4 bc each)
    const int tg  = tid >> 5;           // t group (4 t each)

    for (int idx = tid; idx < 96 * 32; idx += 256) {
        int l = idx >> 5, tt = idx & 31;
        int t = t0 + tt;
        pcts[idx] = (t < NLAT) ? pct[(m * 96 + l) * NLAT + t] : 0.f;
    }
    if (tid < 32) {
        int t = t0 + tid;
        ofs[tid] = (t < NLAT) ? off[t * 96 + m] : 0.f;
    }
    __syncthreads();

    float aR[4][4], aI[4][4];           // [j:t][q:bc]
#pragma unroll
    for (int j = 0; j < 4; ++j)
#pragma unroll
        for (int q = 0; q < 4; ++q) { aR[j][q] = 0.f; aI[j][q] = 0.f; }

    const float* __restrict__ xrp = xTr + m * 96 * 256 + bc0 + bcg * 4;
    const float* __restrict__ xip = xTi + m * 96 * 256 + bc0 + bcg * 4;

    for (int l = 0; l < 96; ++l) {
        float4 xr = *(const float4*)(xrp + l * 256);
        float4 xi = *(const float4*)(xip + l * 256);
        float4 pv = *(const float4*)&pcts[l * 32 + tg * 4];
        float pj[4] = {pv.x, pv.y, pv.z, pv.w};
        float xrq[4] = {xr.x, xr.y, xr.z, xr.w};
        float xiq[4] = {xi.x, xi.y, xi.z, xi.w};
#pragma unroll
        for (int j = 0; j < 4; ++j)
#pragma unroll
            for (int q = 0; q < 4; ++q) {
                aR[j][q] = fmaf(pj[j], xrq[q], aR[j][q]);
                aI[j][q] = fmaf(pj[j], xiq[q], aI[j][q]);
            }
    }

    const float sc = (m == 0) ? 1.f : 2.f;
#pragma unroll
    for (int j = 0; j < 4; ++j) {
        int t = t0 + tg * 4 + j;
        if (t < NLAT) {
            float so, co;
            __sincosf(ofs[tg * 4 + j], &so, &co);
            co *= sc; so *= sc;
            float2 v[4];
#pragma unroll
            for (int q = 0; q < 4; ++q) {
                v[q].x = aR[j][q] * co - aI[j][q] * so;
                v[q].y = aR[j][q] * so + aI[j][q] * co;
            }
            float4* dst = (float4*)(X + (t * 96 + m) * 256 + bc0 + bcg * 4);
            dst[0] = make_float4(v[0].x, v[0].y, v[1].x, v[1].y);
            dst[1] = make_float4(v[2].x, v[2].y, v[3].x, v[3].y);
        }
    }
}

// ---------------- kernel 3: per-ring direct inverse real DFT ----------------
// y[p] = sum_m (Xr[m] cos(2pi m p/n) - Xi[m] sin(2pi m p/n))  (X pre-scaled;
// Nyquist m=n/2 contributes an extra pass with 0.5 to undo the folded x2).
// Thread tile: 8p x 4bc -> 2 ds_read_b128 per m feed 64 data-FMA + 32 rot-FMA.
__global__ __launch_bounds__(256) void k_dft(
        const float2* __restrict__ X, float* __restrict__ out) {
    __shared__ float xsr[96][32];
    __shared__ float xsi[96][32];
    const int t    = blockIdx.x;        // 0..254
    const int bc0  = blockIdx.y * 32;
    const int tid  = threadIdx.x;
    const int pslot = tid & 31;
    const int bcg   = tid >> 5;         // 8 groups of 4 bc

    int n, roff;
    ring_params(t, n, roff);
    const int half = n >> 1;

    for (int idx = tid; idx < 96 * 32; idx += 256) {
        int m = idx >> 5, b = idx & 31;
        float2 v = X[(t * 96 + m) * 256 + bc0 + b];
        xsr[m][b] = v.x;
        xsi[m][b] = v.y;
    }
    __syncthreads();

    const int np  = (pslot < n) ? ((n - pslot + 31) >> 5) : 0;
    const int mhi = (half <= 95) ? (half - 1) : 95;

    float c[8], s[8], y[8][4];
    float cd, sd;
    {
        float delta = 6.28318530717958647692f / (float)n;
        __sincosf((float)pslot * delta, &sd, &cd);           // rot by delta*? no:
    }
    // rotation step angle differs per k only in initial phase; step itself is
    // p * delta with p = pslot + 32k -> step angle = (pslot+32k)*delta, distinct
    // per k. Store per-k step cos/sin.
    float cdk[8], sdk[8];
    {
        float delta = 6.28318530717958647692f / (float)n;
#pragma unroll
        for (int k = 0; k < 8; ++k) {
            if (k < np) {
                float ang = (float)(pslot + 32 * k) * delta;
                __sincosf(ang, &sdk[k], &cdk[k]);
            } else { sdk[k] = 0.f; cdk[k] = 1.f; }
            c[k] = 1.f; s[k] = 0.f;
#pragma unroll
            for (int q = 0; q < 4; ++q) y[k][q] = 0.f;
        }
    }

    for (int m = 0; m <= mhi; ++m) {
        float4 vr = *(const float4*)&xsr[m][bcg * 4];
        float4 vi = *(const float4*)&xsi[m][bcg * 4];
        float vrq[4] = {vr.x, vr.y, vr.z, vr.w};
        float viq[4] = {vi.x, vi.y, vi.z, vi.w};
#pragma unroll
        for (int k = 0; k < 8; ++k) {
            if (k < np) {
                float ck = c[k], sk = s[k];
#pragma unroll
                for (int q = 0; q < 4; ++q)
                    y[k][q] = fmaf(vrq[q], ck, fmaf(viq[q], -sk, y[k][q]));
                c[k] = ck * cdk[k] - sk * sdk[k];
                s[k] = sk * cdk[k] + ck * sdk[k];
            }
        }
    }

    if (half <= 95) {                   // Nyquist: X carries x2, need x1
        float4 vr = *(const float4*)&xsr[half][bcg * 4];
        float4 vi = *(const float4*)&xsi[half][bcg * 4];
        float vrq[4] = {vr.x, vr.y, vr.z, vr.w};
        float viq[4] = {vi.x, vi.y, vi.z, vi.w};
#pragma unroll
        for (int k = 0; k < 8; ++k) {
            if (k < np) {
#pragma unroll
                for (int q = 0; q < 4; ++q)
                    y[k][q] = fmaf(vrq[q], 0.5f * c[k],
                              fmaf(viq[q], -0.5f * s[k], y[k][q]));
            }
        }
    }

#pragma unroll
    for (int k = 0; k < 8; ++k) {
        if (k < np) {
            int p = pslot + 32 * k;
#pragma unroll
            for (int q = 0; q < 4; ++q)
                out[(bc0 + bcg * 4 + q) * NPIX + roff + p] = y[k][q];
        }
    }
}

// ---------------- launcher --------------------------------------------------
extern "C" void kernel_launch(void* const* d_in, const int* in_sizes, int n_in,
                              void* d_out, int out_size, void* d_ws, size_t ws_size,
                              hipStream_t stream) {
    const float* xr  = (const float*)d_in[0];   // (4,64,96,96)
    const float* xi  = (const float*)d_in[1];   // (4,64,96,96)
    const float* pct = (const float*)d_in[2];   // (96,96,255)
    const float* off = (const float*)d_in[3];   // (255,96)
    float* out = (float*)d_out;                 // (4,64,49152)

    float* ws  = (float*)d_ws;
    float* xTr = ws;                        // 96*96*256 floats
    float* xTi = ws + 2359296;              // 96*96*256 floats
    float2* X  = (float2*)(ws + 4718592);   // 255*96*256 float2

    k_transpose<<<dim3(96, 8, 6), dim3(32, 8), 0, stream>>>(xr, xi, xTr, xTi);
    k_legendre<<<dim3(96, 8, 2), 256, 0, stream>>>(xTr, xTi, pct, off, X);
    k_dft<<<dim3(NLAT, 8), 256, 0, stream>>>(X, out);
}

// Round 4
// 250.134 us; speedup vs baseline: 1.2345x; 1.2345x over previous
//
#include <hip/hip_runtime.h>
#include <hip/hip_bf16.h>
#include <math.h>

#define NLAT 255
#define NPIX 49152

// ---------------- ring geometry (NSIDE=64, compile-time closed forms) -------
__device__ __forceinline__ void ring_params(int t, int& n, int& roff) {
    if (t < 63)        { n = 4 * (t + 1); roff = 2 * t * (t + 1); }
    else if (t <= 191) { n = 256;         roff = 8064 + 256 * (t - 63); }
    else               { int w = 255 - t; n = 4 * w; roff = 49152 - 2 * w * (w + 1); }
}

// ---------------- kernel 1: transpose x[bc][l][m] -> xT[m][l][bc] -----------
__global__ __launch_bounds__(256) void k_transpose(
        const float* __restrict__ xr, const float* __restrict__ xi,
        float* __restrict__ xTr, float* __restrict__ xTi) {
    __shared__ float tile[32][33];
    const int l   = blockIdx.x;          // 0..95
    const int bc0 = blockIdx.y * 32;     // 0..224
    const int z   = blockIdx.z;          // 0..5
    const int comp = z / 3;
    const int m0   = (z % 3) * 32;
    const float* in  = comp ? xi : xr;
    float*       out = comp ? xTi : xTr;
    const int tx = threadIdx.x;          // 0..31
    const int ty = threadIdx.y;          // 0..7
#pragma unroll
    for (int j = 0; j < 4; ++j) {
        int bcl = ty + j * 8;
        tile[bcl][tx] = in[((bc0 + bcl) * 96 + l) * 96 + m0 + tx];
    }
    __syncthreads();
#pragma unroll
    for (int j = 0; j < 4; ++j) {
        int ml = ty + j * 8;
        out[((m0 + ml) * 96 + l) * 256 + bc0 + tx] = tile[tx][ml];
    }
}

// ---------------- kernel 2: Legendre contraction + phase --------------------
// X[t][m][bc] = sc_m * e^{i off[t,m]} * sum_l pct[m,l,t] * x[bc,l,m]
// sc_m = 1 for m=0, 2 otherwise (irfft interior doubling folded in here).
// Thread tile: 8t x 4bc -> 64 FMA per (2 global + 2 LDS) loads. Block tile
// 64t x 128bc. No divergence in the hot loop.
__global__ __launch_bounds__(256) void k_legendre(
        const float* __restrict__ xTr, const float* __restrict__ xTi,
        const float* __restrict__ pct, const float* __restrict__ off,
        float2* __restrict__ X) {
    __shared__ float pcts[96][64];      // [l][tt]
    __shared__ float ofs[64];
    const int m   = blockIdx.x;         // 0..95
    const int t0  = blockIdx.y * 64;    // 0,64,128,192
    const int bc0 = blockIdx.z * 128;   // 0 or 128
    const int tid = threadIdx.x;
    const int bcg = tid & 31;           // 32 bc groups (4 bc each)
    const int tg  = tid >> 5;           // 8 t groups (8 t each)

    for (int idx = tid; idx < 96 * 64; idx += 256) {
        int l = idx >> 6, tt = idx & 63;
        int t = t0 + tt;
        pcts[l][tt] = (t < NLAT) ? pct[(m * 96 + l) * NLAT + t] : 0.f;
    }
    if (tid < 64) {
        int t = t0 + tid;
        ofs[tid] = (t < NLAT) ? off[t * 96 + m] : 0.f;
    }
    __syncthreads();

    float aR[8][4], aI[8][4];
#pragma unroll
    for (int j = 0; j < 8; ++j)
#pragma unroll
        for (int q = 0; q < 4; ++q) { aR[j][q] = 0.f; aI[j][q] = 0.f; }

    const float* __restrict__ xrp = xTr + m * 96 * 256 + bc0 + bcg * 4;
    const float* __restrict__ xip = xTi + m * 96 * 256 + bc0 + bcg * 4;

    for (int l = 0; l < 96; ++l) {
        float4 xr = *(const float4*)(xrp + l * 256);
        float4 xi = *(const float4*)(xip + l * 256);
        float4 p0 = *(const float4*)&pcts[l][tg * 8];
        float4 p1 = *(const float4*)&pcts[l][tg * 8 + 4];
        float pj[8]  = {p0.x, p0.y, p0.z, p0.w, p1.x, p1.y, p1.z, p1.w};
        float xrq[4] = {xr.x, xr.y, xr.z, xr.w};
        float xiq[4] = {xi.x, xi.y, xi.z, xi.w};
#pragma unroll
        for (int j = 0; j < 8; ++j)
#pragma unroll
            for (int q = 0; q < 4; ++q) {
                aR[j][q] = fmaf(pj[j], xrq[q], aR[j][q]);
                aI[j][q] = fmaf(pj[j], xiq[q], aI[j][q]);
            }
    }

    const float sc = (m == 0) ? 1.f : 2.f;
#pragma unroll
    for (int j = 0; j < 8; ++j) {
        int tt = tg * 8 + j;
        int t  = t0 + tt;
        if (t < NLAT) {
            float so, co;
            __sincosf(ofs[tt], &so, &co);
            co *= sc; so *= sc;
            float4* dst = (float4*)(X + (t * 96 + m) * 256 + bc0 + bcg * 4);
            dst[0] = make_float4(aR[j][0] * co - aI[j][0] * so,
                                 aR[j][0] * so + aI[j][0] * co,
                                 aR[j][1] * co - aI[j][1] * so,
                                 aR[j][1] * so + aI[j][1] * co);
            dst[1] = make_float4(aR[j][2] * co - aI[j][2] * so,
                                 aR[j][2] * so + aI[j][2] * co,
                                 aR[j][3] * co - aI[j][3] * so,
                                 aR[j][3] * so + aI[j][3] * co);
        }
    }
}

// ---------------- kernel 3a: equatorial rings (n=256, uniform) --------------
// half=128>95 -> all 96 m interior (scale already folded), no Nyquist, all
// 8 p-slots valid for every lane: ZERO guards in the hot loop.
__global__ __launch_bounds__(256) void k_dft_eq(
        const float2* __restrict__ X, float* __restrict__ out) {
    __shared__ float xsr[96][32];
    __shared__ float xsi[96][32];
    const int t    = 63 + blockIdx.x;   // 63..191
    const int bc0  = blockIdx.y * 32;
    const int tid  = threadIdx.x;
    const int pslot = tid & 31;
    const int bcg   = tid >> 5;
    const int roff  = 8064 + 256 * (t - 63);

    for (int idx = tid; idx < 96 * 32; idx += 256) {
        int m = idx >> 5, b = idx & 31;
        float2 v = X[(t * 96 + m) * 256 + bc0 + b];
        xsr[m][b] = v.x;
        xsi[m][b] = v.y;
    }
    __syncthreads();

    const float delta = 6.28318530717958647692f / 256.f;
    float c[8], s[8], cdk[8], sdk[8], y[8][4];
#pragma unroll
    for (int k = 0; k < 8; ++k) {
        __sincosf((float)(pslot + 32 * k) * delta, &sdk[k], &cdk[k]);
        c[k] = 1.f; s[k] = 0.f;
#pragma unroll
        for (int q = 0; q < 4; ++q) y[k][q] = 0.f;
    }

    for (int m = 0; m < 96; ++m) {
        float4 vr = *(const float4*)&xsr[m][bcg * 4];
        float4 vi = *(const float4*)&xsi[m][bcg * 4];
        float vrq[4] = {vr.x, vr.y, vr.z, vr.w};
        float viq[4] = {vi.x, vi.y, vi.z, vi.w};
#pragma unroll
        for (int k = 0; k < 8; ++k) {
            float ck = c[k], sk = s[k];
#pragma unroll
            for (int q = 0; q < 4; ++q)
                y[k][q] = fmaf(vrq[q], ck, fmaf(viq[q], -sk, y[k][q]));
            c[k] = fmaf(ck, cdk[k], -sk * sdk[k]);
            s[k] = fmaf(sk, cdk[k],  ck * sdk[k]);
        }
    }

#pragma unroll
    for (int k = 0; k < 8; ++k) {
        int p = pslot + 32 * k;
#pragma unroll
        for (int q = 0; q < 4; ++q)
            out[(bc0 + bcg * 4 + q) * NPIX + roff + p] = y[k][q];
    }
}

// ---------------- kernel 3b: polar rings (n=4..252) -------------------------
// k fully unrolled with NO guards; invalid p compute garbage, masked at the
// store only. m-bound and Nyquist are wave-uniform scalar conditions.
__global__ __launch_bounds__(256) void k_dft_polar(
        const float2* __restrict__ X, float* __restrict__ out) {
    __shared__ float xsr[96][32];
    __shared__ float xsi[96][32];
    const int i    = blockIdx.x;        // 0..125
    const int t    = (i < 63) ? i : (129 + i);   // north 0..62, south 192..254
    const int bc0  = blockIdx.y * 32;
    const int tid  = threadIdx.x;
    const int pslot = tid & 31;
    const int bcg   = tid >> 5;

    int n, roff;
    ring_params(t, n, roff);
    const int  half = n >> 1;
    const bool nyq  = (half <= 95);
    const int  mhi  = nyq ? (half - 1) : 95;

    for (int idx = tid; idx < 96 * 32; idx += 256) {
        int m = idx >> 5, b = idx & 31;
        float2 v = X[(t * 96 + m) * 256 + bc0 + b];
        xsr[m][b] = v.x;
        xsi[m][b] = v.y;
    }
    __syncthreads();

    const float delta = 6.28318530717958647692f / (float)n;
    float c[8], s[8], cdk[8], sdk[8], y[8][4];
#pragma unroll
    for (int k = 0; k < 8; ++k) {
        __sincosf((float)(pslot + 32 * k) * delta, &sdk[k], &cdk[k]);
        c[k] = 1.f; s[k] = 0.f;
#pragma unroll
        for (int q = 0; q < 4; ++q) y[k][q] = 0.f;
    }

    for (int m = 0; m <= mhi; ++m) {
        float4 vr = *(const float4*)&xsr[m][bcg * 4];
        float4 vi = *(const float4*)&xsi[m][bcg * 4];
        float vrq[4] = {vr.x, vr.y, vr.z, vr.w};
        float viq[4] = {vi.x, vi.y, vi.z, vi.w};
#pragma unroll
        for (int k = 0; k < 8; ++k) {
            float ck = c[k], sk = s[k];
#pragma unroll
            for (int q = 0; q < 4; ++q)
                y[k][q] = fmaf(vrq[q], ck, fmaf(viq[q], -sk, y[k][q]));
            c[k] = fmaf(ck, cdk[k], -sk * sdk[k]);
            s[k] = fmaf(sk, cdk[k],  ck * sdk[k]);
        }
    }

    if (nyq) {                          // m = half: X carries x2, need x1
        float4 vr = *(const float4*)&xsr[half][bcg * 4];
        float4 vi = *(const float4*)&xsi[half][bcg * 4];
        float vrq[4] = {vr.x, vr.y, vr.z, vr.w};
        float viq[4] = {vi.x, vi.y, vi.z, vi.w};
#pragma unroll
        for (int k = 0; k < 8; ++k) {
            float ck = 0.5f * c[k], sk = 0.5f * s[k];
#pragma unroll
            for (int q = 0; q < 4; ++q)
                y[k][q] = fmaf(vrq[q], ck, fmaf(viq[q], -sk, y[k][q]));
        }
    }

#pragma unroll
    for (int k = 0; k < 8; ++k) {
        int p = pslot + 32 * k;
        if (p < n) {
#pragma unroll
            for (int q = 0; q < 4; ++q)
                out[(bc0 + bcg * 4 + q) * NPIX + roff + p] = y[k][q];
        }
    }
}

// ---------------- launcher --------------------------------------------------
extern "C" void kernel_launch(void* const* d_in, const int* in_sizes, int n_in,
                              void* d_out, int out_size, void* d_ws, size_t ws_size,
                              hipStream_t stream) {
    const float* xr  = (const float*)d_in[0];   // (4,64,96,96)
    const float* xi  = (const float*)d_in[1];   // (4,64,96,96)
    const float* pct = (const float*)d_in[2];   // (96,96,255)
    const float* off = (const float*)d_in[3];   // (255,96)
    float* out = (float*)d_out;                 // (4,64,49152)

    float* ws  = (float*)d_ws;
    float* xTr = ws;                        // 96*96*256 floats
    float* xTi = ws + 2359296;              // 96*96*256 floats
    float2* X  = (float2*)(ws + 4718592);   // 255*96*256 float2

    k_transpose<<<dim3(96, 8, 6), dim3(32, 8), 0, stream>>>(xr, xi, xTr, xTi);
    k_legendre<<<dim3(96, 4, 2), 256, 0, stream>>>(xTr, xTi, pct, off, X);
    k_dft_eq<<<dim3(129, 8), 256, 0, stream>>>(X, out);
    k_dft_polar<<<dim3(126, 8), 256, 0, stream>>>(X, out);
}

// Round 5
// 173.690 us; speedup vs baseline: 1.7778x; 1.4401x over previous
//
#include <hip/hip_runtime.h>
#include <hip/hip_bf16.h>
#include <math.h>

#define NLAT 255
#define NPIX 49152
#define PI_F 3.14159265358979323846f

typedef _Float16 half_t;
typedef half_t half8 __attribute__((ext_vector_type(8)));   // A/B frag: 4 VGPRs
typedef float  f32x4 __attribute__((ext_vector_type(4)));   // C/D frag

// ---------------- ring geometry (NSIDE=64, compile-time closed forms) -------
__device__ __forceinline__ void ring_params(int t, int& n, int& roff) {
    if (t < 63)        { n = 4 * (t + 1); roff = 2 * t * (t + 1); }
    else if (t <= 191) { n = 256;         roff = 8064 + 256 * (t - 63); }
    else               { int w = 255 - t; n = 4 * w; roff = 49152 - 2 * w * (w + 1); }
}

// ============ prep 1: twiddle matrix W[pix][192] fp16 =======================
// W[p][2m] = sc_m*cos(m*phi), W[p][2m+1] = -sc_m*sin(m*phi), phi = 2pi p/n + alpha_t.
// Folds: longitude phase offset (off = alpha*m), irfft interior x2, Nyquist
// imag-drop (sc=1, sin(pi p)=0 via formula), m>n/2 truncation (sc=0).
__global__ __launch_bounds__(256) void k_prep_w(half_t* __restrict__ W) {
    int gid   = blockIdx.x * 256 + threadIdx.x;
    int chunk = gid & 31;            // k-chunk of 8 (4 m); only 0..23 used
    int pix   = gid >> 5;
    if (chunk >= 24 || pix >= NPIX) return;

    int t, p;
    if (pix < 8064) {                                   // north cap
        int tt = (int)((sqrtf((float)(2 * pix + 1)) - 1.0f) * 0.5f);
        while (2 * tt * (tt + 1) > pix) --tt;
        while (2 * (tt + 1) * (tt + 2) <= pix) ++tt;
        t = tt; p = pix - 2 * tt * (tt + 1);
    } else if (pix < 41088) {                           // equatorial
        t = 63 + ((pix - 8064) >> 8); p = (pix - 8064) & 255;
    } else {                                            // south cap
        int r = NPIX - 1 - pix;
        int tt = (int)((sqrtf((float)(2 * r + 1)) - 1.0f) * 0.5f);
        while (2 * tt * (tt + 1) > r) --tt;
        while (2 * (tt + 1) * (tt + 2) <= r) ++tt;
        int w = tt + 1;
        t = 254 - tt;
        p = pix - (NPIX - 2 * w * (w + 1));
    }
    int n, roff; ring_params(t, n, roff);
    const int n2 = n >> 1;
    float alpha = (t < 63)   ? PI_F / (4.0f * (float)(t + 1))
                : (t <= 191) ? (((t - 62) & 1) ? PI_F / 256.0f : 0.0f)
                :              PI_F / (4.0f * (float)(255 - t));
    float phi = 6.28318530717958647692f * (float)p / (float)n + alpha;

    int m0 = chunk * 4;
    float c, s, cd, sd;
    __sincosf((float)m0 * phi, &s, &c);
    __sincosf(phi, &sd, &cd);
    half8 v;
#pragma unroll
    for (int j = 0; j < 4; ++j) {
        int m = m0 + j;
        float sc = (m == 0) ? 1.f : (m < n2) ? 2.f : (m == n2) ? 1.f : 0.f;
        v[2 * j]     = (half_t)(sc * c);
        v[2 * j + 1] = (half_t)(-sc * s);
        float cn = c * cd - s * sd; s = s * cd + c * sd; c = cn;
    }
    *(half8*)(W + (size_t)pix * 192 + chunk * 8) = v;
}

// ============ prep 2: pct[m][l][t] -> pctT[m][t][l] fp16 (t padded to 256) ==
__global__ __launch_bounds__(256) void k_prep_pct(
        const float* __restrict__ pct, half_t* __restrict__ pctT) {
    __shared__ float tile[96][33];
    const int m = blockIdx.x, t0 = blockIdx.y * 32;
    const int tid = threadIdx.x;
    for (int idx = tid; idx < 96 * 32; idx += 256) {
        int l = idx >> 5, tt = idx & 31, t = t0 + tt;
        tile[l][tt] = (t < NLAT) ? pct[((size_t)m * 96 + l) * NLAT + t] : 0.f;
    }
    __syncthreads();
    for (int idx = tid; idx < 96 * 32; idx += 256) {
        int tt = idx / 96, l = idx - tt * 96;
        pctT[((size_t)m * 256 + t0 + tt) * 96 + l] = (half_t)tile[l][tt];
    }
}

// ============ prep 3: x[bc][l][m] -> xh[c][m][l/8][bc][l%8] fp16 ============
__global__ void k_prep_x(const float* __restrict__ xr, const float* __restrict__ xi,
                         half_t* __restrict__ xh) {
    __shared__ float tile[32][33];
    const int l   = blockIdx.x;          // 0..95
    const int bc0 = blockIdx.y * 32;
    const int z   = blockIdx.z;          // comp*3 + mtile
    const int comp = z / 3, m0 = (z % 3) * 32;
    const float* in = comp ? xi : xr;
    const int tx = threadIdx.x, ty = threadIdx.y;
#pragma unroll
    for (int j = 0; j < 4; ++j) {
        int bcl = ty + j * 8;
        tile[bcl][tx] = in[((size_t)(bc0 + bcl) * 96 + l) * 96 + m0 + tx];
    }
    __syncthreads();
#pragma unroll
    for (int j = 0; j < 4; ++j) {
        int ml = ty + j * 8;
        xh[((((size_t)(comp * 96 + m0 + ml)) * 12 + (l >> 3)) * 256 + bc0 + tx) * 8
           + (l & 7)] = (half_t)tile[tx][ml];
    }
}

// ============ stage 1: Legendre GEMMs (MFMA) ================================
// For m-group of 4: C[t][bc] = sum_l pctT[m][t][l] * xh[c][m][l][bc], K=96.
// Block tile M=64 x N=32, 4 waves (2 in t, 2 in bc), wave tile 32x16.
// Epilogue packs 4m x {re,im} = 8 consecutive k into one 16B Xp store.
__global__ __launch_bounds__(256) void k_leg(
        const half_t* __restrict__ pctT, const half_t* __restrict__ xh,
        half_t* __restrict__ Xp) {
    const int mg  = blockIdx.x;          // 0..23
    const int t0  = blockIdx.y * 64;
    const int bc0 = blockIdx.z * 32;
    const int wid = threadIdx.x >> 6, lane = threadIdx.x & 63;
    const int wm = wid & 1, wn = wid >> 1;
    const int row = lane & 15, quad = lane >> 4;
    const int tbase = t0 + wm * 32;
    const int bc    = bc0 + wn * 16 + row;

    f32x4 acc[4][2][2];                  // [mi][comp][mt]
#pragma unroll
    for (int a = 0; a < 4; ++a)
#pragma unroll
        for (int b = 0; b < 2; ++b)
#pragma unroll
            for (int d = 0; d < 2; ++d) acc[a][b][d] = (f32x4)0.f;

#pragma unroll
    for (int k0 = 0; k0 < 96; k0 += 32) {
        const int kA = k0 + quad * 8;
        half8 af[4][2], bf[4][2];
#pragma unroll
        for (int mi = 0; mi < 4; ++mi) {
            const int m = mg * 4 + mi;
#pragma unroll
            for (int mt = 0; mt < 2; ++mt)
                af[mi][mt] = *(const half8*)(pctT +
                    ((size_t)m * 256 + tbase + mt * 16 + row) * 96 + kA);
#pragma unroll
            for (int c = 0; c < 2; ++c)
                bf[mi][c] = *(const half8*)(xh +
                    ((((size_t)(c * 96 + m)) * 12 + (k0 >> 3) + quad) * 256 + bc) * 8);
        }
#pragma unroll
        for (int mi = 0; mi < 4; ++mi)
#pragma unroll
            for (int c = 0; c < 2; ++c)
#pragma unroll
                for (int mt = 0; mt < 2; ++mt)
                    acc[mi][c][mt] = __builtin_amdgcn_mfma_f32_16x16x32_f16(
                        af[mi][mt], bf[mi][c], acc[mi][c][mt], 0, 0, 0);
    }

#pragma unroll
    for (int mt = 0; mt < 2; ++mt)
#pragma unroll
        for (int r = 0; r < 4; ++r) {
            const int t = tbase + mt * 16 + quad * 4 + r;
            half8 v;
#pragma unroll
            for (int mi = 0; mi < 4; ++mi) {
                v[2 * mi]     = (half_t)acc[mi][0][mt][r];
                v[2 * mi + 1] = (half_t)acc[mi][1][mt][r];
            }
            *(half8*)(Xp + (((size_t)t * 24 + mg) * 256 + bc) * 8) = v;
        }
}

// ============ stage 2a: equatorial ring DFT (MFMA) ==========================
// out[p][bc] = sum_k W[roff+p][k] * Xp[t][k][bc], K=192, M=N=256 per ring.
// Block M=64 x N=64, 4 waves along N; wave M=64(mt=4) x N=16.
__global__ __launch_bounds__(256) void k_dft_eq(
        const half_t* __restrict__ W, const half_t* __restrict__ Xp,
        float* __restrict__ out) {
    const int t   = 63 + blockIdx.x;
    const int p0  = blockIdx.y * 64;
    const int bc0 = blockIdx.z * 64;
    const int wid = threadIdx.x >> 6, lane = threadIdx.x & 63;
    const int row = lane & 15, quad = lane >> 4;
    const int roff = 8064 + 256 * (t - 63);
    const int bc   = bc0 + wid * 16 + row;

    f32x4 acc[4];
#pragma unroll
    for (int a = 0; a < 4; ++a) acc[a] = (f32x4)0.f;

#pragma unroll
    for (int k0 = 0; k0 < 192; k0 += 32) {
        const int kA = k0 + quad * 8;
        half8 b = *(const half8*)(Xp + (((size_t)t * 24 + (k0 >> 3) + quad) * 256 + bc) * 8);
#pragma unroll
        for (int mt = 0; mt < 4; ++mt) {
            half8 a = *(const half8*)(W + (size_t)(roff + p0 + mt * 16 + row) * 192 + kA);
            acc[mt] = __builtin_amdgcn_mfma_f32_16x16x32_f16(a, b, acc[mt], 0, 0, 0);
        }
    }
#pragma unroll
    for (int mt = 0; mt < 4; ++mt) {
        const int p = p0 + mt * 16 + quad * 4;
        float4 v = make_float4(acc[mt][0], acc[mt][1], acc[mt][2], acc[mt][3]);
        *(float4*)(out + (size_t)bc * NPIX + roff + p) = v;
    }
}

// ============ stage 2b: polar ring DFT (MFMA) ===============================
// Variable n=4w; M-tiles of 16, garbage rows (p>=n) computed and dropped at
// the store. K truncated to the ring's active 2*(mh+1) columns.
__global__ __launch_bounds__(256) void k_dft_polar(
        const half_t* __restrict__ W, const half_t* __restrict__ Xp,
        float* __restrict__ out) {
    const int i = blockIdx.x;                 // 0..125
    const int t = (i < 63) ? i : 129 + i;
    int n, roff; ring_params(t, n, roff);
    const int p0 = blockIdx.y * 16;
    if (p0 >= n) return;
    const int bc0 = blockIdx.z * 64;
    const int wid = threadIdx.x >> 6, lane = threadIdx.x & 63;
    const int row = lane & 15, quad = lane >> 4;
    const int bc = bc0 + wid * 16 + row;

    const int mh = min(95, n >> 1);
    const int ks = (2 * (mh + 1) + 31) >> 5;  // active k-steps

    f32x4 acc = (f32x4)0.f;
    for (int kk = 0; kk < ks; ++kk) {
        const int k0 = kk * 32, kA = k0 + quad * 8;
        half8 a = *(const half8*)(W + (size_t)(roff + p0 + row) * 192 + kA);
        half8 b = *(const half8*)(Xp + (((size_t)t * 24 + (k0 >> 3) + quad) * 256 + bc) * 8);
        acc = __builtin_amdgcn_mfma_f32_16x16x32_f16(a, b, acc, 0, 0, 0);
    }
    const int p = p0 + quad * 4;
    if (p < n) {
        float4 v = make_float4(acc[0], acc[1], acc[2], acc[3]);
        *(float4*)(out + (size_t)bc * NPIX + roff + p) = v;
    }
}

// ---------------- launcher --------------------------------------------------
extern "C" void kernel_launch(void* const* d_in, const int* in_sizes, int n_in,
                              void* d_out, int out_size, void* d_ws, size_t ws_size,
                              hipStream_t stream) {
    const float* xr  = (const float*)d_in[0];   // (4,64,96,96)
    const float* xi  = (const float*)d_in[1];   // (4,64,96,96)
    const float* pct = (const float*)d_in[2];   // (96,96,255)
    // d_in[3] (offset) recomputed analytically: off[t][m] = alpha_t * m
    float* out = (float*)d_out;                 // (4,64,49152)

    char* ws = (char*)d_ws;
    half_t* W    = (half_t*)ws;                                  // (49152+16)*192
    half_t* pctT = (half_t*)(ws + 18880512);                     // 96*256*96
    half_t* xh   = (half_t*)(ws + 18880512 + 4718592);           // 2*96*12*256*8
    half_t* Xp   = (half_t*)(ws + 18880512 + 4718592 + 9437184); // 256*24*256*8

    k_prep_w  <<<dim3(6144), 256, 0, stream>>>(W);
    k_prep_pct<<<dim3(96, 8), 256, 0, stream>>>(pct, pctT);
    k_prep_x  <<<dim3(96, 8, 6), dim3(32, 8), 0, stream>>>(xr, xi, xh);
    k_leg     <<<dim3(24, 4, 8), 256, 0, stream>>>(pctT, xh, Xp);
    k_dft_eq  <<<dim3(129, 4, 4), 256, 0, stream>>>(W, Xp, out);
    k_dft_polar<<<dim3(126, 16, 4), 256, 0, stream>>>(W, Xp, out);
}

// Round 6
// 167.602 us; speedup vs baseline: 1.8424x; 1.0363x over previous
//
#include <hip/hip_runtime.h>
#include <hip/hip_bf16.h>
#include <math.h>

#define NLAT 255
#define NPIX 49152
#define PI_F 3.14159265358979323846f

typedef _Float16 half_t;
typedef half_t half8 __attribute__((ext_vector_type(8)));   // A/B frag: 4 VGPRs
typedef float  f32x4 __attribute__((ext_vector_type(4)));   // C/D frag

// ---------------- ring geometry (NSIDE=64, compile-time closed forms) -------
__device__ __forceinline__ void ring_params(int t, int& n, int& roff) {
    if (t < 63)        { n = 4 * (t + 1); roff = 2 * t * (t + 1); }
    else if (t <= 191) { n = 256;         roff = 8064 + 256 * (t - 63); }
    else               { int w = 255 - t; n = 4 * w; roff = 49152 - 2 * w * (w + 1); }
}

// ============ merged prep kernel ============================================
// blocks [0,768):        pct[m][l][t] -> pctT[m][t][l] fp16 (t padded to 256)
// blocks [768,5376):     x[bc][l][m]  -> xh[c][m][l/8][bc][l%8] fp16
// blocks [5376,11520):   build twiddle W[pix][192] fp16:
//   W[p][2m]=sc_m*cos(m*phi), W[p][2m+1]=-sc_m*sin(m*phi), phi=2pi p/n+alpha_t
//   folds: phase offset (off=alpha*m), irfft interior x2, m-crop (sc=0),
//   Nyquist (sc=1; Re{X e^{i(n/2)phi}} form is exact incl. alpha).
__global__ __launch_bounds__(256) void k_prep(
        const float* __restrict__ pct,
        const float* __restrict__ xr, const float* __restrict__ xi,
        half_t* __restrict__ pctT, half_t* __restrict__ xh,
        half_t* __restrict__ W) {
    __shared__ float smem[96 * 33];
    const int bx  = blockIdx.x;
    const int tid = threadIdx.x;

    if (bx < 768) {                     // ---- pct transpose ----
        const int m = bx >> 3, t0 = (bx & 7) * 32;
        for (int idx = tid; idx < 96 * 32; idx += 256) {
            int l = idx >> 5, tt = idx & 31, t = t0 + tt;
            smem[l * 33 + tt] = (t < NLAT) ? pct[((size_t)m * 96 + l) * NLAT + t] : 0.f;
        }
        __syncthreads();
        for (int idx = tid; idx < 96 * 32; idx += 256) {
            int tt = idx / 96, l = idx - tt * 96;
            pctT[((size_t)m * 256 + t0 + tt) * 96 + l] = (half_t)smem[l * 33 + tt];
        }
    } else if (bx < 5376) {             // ---- x pack/transpose ----
        const int id  = bx - 768;
        const int z   = id / 768;       // comp*3 + mtile
        const int rem = id - z * 768;
        const int l   = rem % 96;
        const int bc0 = (rem / 96) * 32;
        const int comp = z / 3, m0 = (z % 3) * 32;
        const float* in = comp ? xi : xr;
        const int tx = tid & 31, ty = tid >> 5;
#pragma unroll
        for (int j = 0; j < 4; ++j) {
            int bcl = ty + j * 8;
            smem[bcl * 33 + tx] = in[((size_t)(bc0 + bcl) * 96 + l) * 96 + m0 + tx];
        }
        __syncthreads();
#pragma unroll
        for (int j = 0; j < 4; ++j) {
            int ml = ty + j * 8;
            xh[((((size_t)(comp * 96 + m0 + ml)) * 12 + (l >> 3)) * 256 + bc0 + tx) * 8
               + (l & 7)] = (half_t)smem[tx * 33 + ml];
        }
    } else {                            // ---- twiddle W ----
        int gid   = (bx - 5376) * 256 + tid;
        int chunk = gid & 31;           // k-chunk of 8 (4 m); only 0..23 used
        int pix   = gid >> 5;
        if (chunk >= 24 || pix >= NPIX) return;

        int t, p;
        if (pix < 8064) {                                   // north cap
            int tt = (int)((sqrtf((float)(2 * pix + 1)) - 1.0f) * 0.5f);
            while (2 * tt * (tt + 1) > pix) --tt;
            while (2 * (tt + 1) * (tt + 2) <= pix) ++tt;
            t = tt; p = pix - 2 * tt * (tt + 1);
        } else if (pix < 41088) {                           // equatorial
            t = 63 + ((pix - 8064) >> 8); p = (pix - 8064) & 255;
        } else {                                            // south cap
            int r = NPIX - 1 - pix;
            int tt = (int)((sqrtf((float)(2 * r + 1)) - 1.0f) * 0.5f);
            while (2 * tt * (tt + 1) > r) --tt;
            while (2 * (tt + 1) * (tt + 2) <= r) ++tt;
            int w = tt + 1;
            t = 254 - tt;
            p = pix - (NPIX - 2 * w * (w + 1));
        }
        int n, roff; ring_params(t, n, roff);
        const int n2 = n >> 1;
        float alpha = (t < 63)   ? PI_F / (4.0f * (float)(t + 1))
                    : (t <= 191) ? (((t - 62) & 1) ? PI_F / 256.0f : 0.0f)
                    :              PI_F / (4.0f * (float)(255 - t));
        float phi = 6.28318530717958647692f * (float)p / (float)n + alpha;

        int m0 = chunk * 4;
        float c, s, cd, sd;
        __sincosf((float)m0 * phi, &s, &c);
        __sincosf(phi, &sd, &cd);
        half8 v;
#pragma unroll
        for (int j = 0; j < 4; ++j) {
            int m = m0 + j;
            float sc = (m == 0) ? 1.f : (m < n2) ? 2.f : (m == n2) ? 1.f : 0.f;
            v[2 * j]     = (half_t)(sc * c);
            v[2 * j + 1] = (half_t)(-sc * s);
            float cn = c * cd - s * sd; s = s * cd + c * sd; c = cn;
        }
        *(half8*)(W + (size_t)pix * 192 + chunk * 8) = v;
    }
}

// ============ stage 1: Legendre GEMMs (MFMA) ================================
// For m-group of 4: C[t][bc] = sum_l pctT[m][t][l] * xh[c][m][l][bc], K=96.
// Block tile M=64 x N=32, 4 waves (2 in t, 2 in bc), wave tile 32x16.
// Epilogue packs 4m x {re,im} = 8 consecutive k into one 16B Xp store.
__global__ __launch_bounds__(256) void k_leg(
        const half_t* __restrict__ pctT, const half_t* __restrict__ xh,
        half_t* __restrict__ Xp) {
    const int mg  = blockIdx.x;          // 0..23
    const int t0  = blockIdx.y * 64;
    const int bc0 = blockIdx.z * 32;
    const int wid = threadIdx.x >> 6, lane = threadIdx.x & 63;
    const int wm = wid & 1, wn = wid >> 1;
    const int row = lane & 15, quad = lane >> 4;
    const int tbase = t0 + wm * 32;
    const int bc    = bc0 + wn * 16 + row;

    f32x4 acc[4][2][2];                  // [mi][comp][mt]
#pragma unroll
    for (int a = 0; a < 4; ++a)
#pragma unroll
        for (int b = 0; b < 2; ++b)
#pragma unroll
            for (int d = 0; d < 2; ++d) acc[a][b][d] = (f32x4)0.f;

#pragma unroll
    for (int k0 = 0; k0 < 96; k0 += 32) {
        const int kA = k0 + quad * 8;
        half8 af[4][2], bf[4][2];
#pragma unroll
        for (int mi = 0; mi < 4; ++mi) {
            const int m = mg * 4 + mi;
#pragma unroll
            for (int mt = 0; mt < 2; ++mt)
                af[mi][mt] = *(const half8*)(pctT +
                    ((size_t)m * 256 + tbase + mt * 16 + row) * 96 + kA);
#pragma unroll
            for (int c = 0; c < 2; ++c)
                bf[mi][c] = *(const half8*)(xh +
                    ((((size_t)(c * 96 + m)) * 12 + (k0 >> 3) + quad) * 256 + bc) * 8);
        }
#pragma unroll
        for (int mi = 0; mi < 4; ++mi)
#pragma unroll
            for (int c = 0; c < 2; ++c)
#pragma unroll
                for (int mt = 0; mt < 2; ++mt)
                    acc[mi][c][mt] = __builtin_amdgcn_mfma_f32_16x16x32_f16(
                        af[mi][mt], bf[mi][c], acc[mi][c][mt], 0, 0, 0);
    }

#pragma unroll
    for (int mt = 0; mt < 2; ++mt)
#pragma unroll
        for (int r = 0; r < 4; ++r) {
            const int t = tbase + mt * 16 + quad * 4 + r;
            half8 v;
#pragma unroll
            for (int mi = 0; mi < 4; ++mi) {
                v[2 * mi]     = (half_t)acc[mi][0][mt][r];
                v[2 * mi + 1] = (half_t)acc[mi][1][mt][r];
            }
            *(half8*)(Xp + (((size_t)t * 24 + mg) * 256 + bc) * 8) = v;
        }
}

// ============ stage 2: unified ring DFT (MFMA), all 255 rings ===============
// out[p][bc] = sum_k W[roff+p][k] * Xp[t][k][bc].  Uniform M=64 p-tiles;
// rows p>=n compute garbage (W row-padded) and are dropped at the store.
// K truncated per ring (wave-uniform ks); cropped m columns have sc=0 in W.
__global__ __launch_bounds__(256) void k_dft(
        const half_t* __restrict__ W, const half_t* __restrict__ Xp,
        float* __restrict__ out) {
    const int t = blockIdx.x;            // 0..254
    int n, roff; ring_params(t, n, roff);
    const int p0 = blockIdx.y * 64;
    if (p0 >= n) return;
    const int bc0 = blockIdx.z * 64;
    const int wid = threadIdx.x >> 6, lane = threadIdx.x & 63;
    const int row = lane & 15, quad = lane >> 4;
    const int bc  = bc0 + wid * 16 + row;

    const int mh = min(95, n >> 1);
    const int ks = (2 * (mh + 1) + 31) >> 5;   // 1..6 active 32-wide k-steps

    f32x4 acc[4];
#pragma unroll
    for (int a = 0; a < 4; ++a) acc[a] = (f32x4)0.f;

    for (int kk = 0; kk < ks; ++kk) {
        const int kA = kk * 32 + quad * 8;
        half8 b = *(const half8*)(Xp + (((size_t)t * 24 + kk * 4 + quad) * 256 + bc) * 8);
#pragma unroll
        for (int mt = 0; mt < 4; ++mt) {
            half8 a = *(const half8*)(W + (size_t)(roff + p0 + mt * 16 + row) * 192 + kA);
            acc[mt] = __builtin_amdgcn_mfma_f32_16x16x32_f16(a, b, acc[mt], 0, 0, 0);
        }
    }
#pragma unroll
    for (int mt = 0; mt < 4; ++mt) {
        const int p = p0 + mt * 16 + quad * 4;
        if (p < n) {                     // n%4==0 -> whole float4 in-bounds
            float4 v = make_float4(acc[mt][0], acc[mt][1], acc[mt][2], acc[mt][3]);
            *(float4*)(out + (size_t)bc * NPIX + roff + p) = v;
        }
    }
}

// ---------------- launcher --------------------------------------------------
extern "C" void kernel_launch(void* const* d_in, const int* in_sizes, int n_in,
                              void* d_out, int out_size, void* d_ws, size_t ws_size,
                              hipStream_t stream) {
    const float* xr  = (const float*)d_in[0];   // (4,64,96,96)
    const float* xi  = (const float*)d_in[1];   // (4,64,96,96)
    const float* pct = (const float*)d_in[2];   // (96,96,255)
    // d_in[3] (offset) recomputed analytically: off[t][m] = alpha_t * m
    float* out = (float*)d_out;                 // (4,64,49152)

    char* ws = (char*)d_ws;
    half_t* W    = (half_t*)ws;                         // (NPIX+64)*192 halfs
    half_t* pctT = (half_t*)(ws + 18923520);            // 96*256*96
    half_t* xh   = (half_t*)(ws + 18923520 + 4718592);  // 2*96*12*256*8
    half_t* Xp   = (half_t*)(ws + 18923520 + 4718592 + 9437184); // 256*24*256*8

    k_prep<<<dim3(11520), 256, 0, stream>>>(pct, xr, xi, pctT, xh, W);
    k_leg <<<dim3(24, 4, 8), 256, 0, stream>>>(pctT, xh, Xp);
    k_dft <<<dim3(255, 4, 4), 256, 0, stream>>>(W, Xp, out);
}